// Round 7
// baseline (418.410 us; speedup 1.0000x reference)
//
#include <hip/hip_runtime.h>
#include <hip/hip_bf16.h>

// Self-attention: B=4, S=2048, D=768, fp32 in/out, bf16 MFMA internally.
// R7: NO-LDS GEMM. All operands are [row][k] bf16, and the 16x16x32 A/B
// fragment is exactly a 16-B load per lane: A[row + lane16][k0 + q*8]. Loading
// fragments straight from global removes LDS staging AND both per-iteration
// barriers — no more whole-CU vmcnt(0) convoy stalls (the R6 counters showed
// MFMA 24%, VALU 21%, HBM 31%, LDS ~35%: stall-bound, nothing saturated).
// The compiler now interleaves next-step loads under MFMAs with fine-grained
// vmcnt, which the barrier structure could never express. L2 absorbs the
// 2x refetch (each 128-B row-line is consumed across q/s within the wave).
// ws: Xb | WqT WkT WvT | Qb Kb Vt | Es

typedef __attribute__((ext_vector_type(8))) short short8;
typedef __attribute__((ext_vector_type(4))) short short4v;
typedef __attribute__((ext_vector_type(4))) float float4v;

static constexpr int B_ = 4, S_ = 2048, D_ = 768;
static constexpr int MS = B_ * S_;  // 8192

__device__ inline short f2bf(float f) {
  __hip_bfloat16 h = __float2bfloat16(f);
  union { __hip_bfloat16 h; short s; } u; u.h = h; return u.s;
}
__device__ inline float bf2f(short s) {
  union { unsigned int u; float f; } c;
  c.u = ((unsigned int)(unsigned short)s) << 16; return c.f;
}

__global__ __launch_bounds__(256)
void cast_f32_bf16(const float* __restrict__ x, short* __restrict__ y, int n) {
  int i = (blockIdx.x * 256 + threadIdx.x) * 4;
  if (i + 3 < n) {
    float4v v = *(const float4v*)(x + i);
    short4v o;
    o.x = f2bf(v.x); o.y = f2bf(v.y); o.z = f2bf(v.z); o.w = f2bf(v.w);
    *(short4v*)(y + i) = o;
  }
}

// T[e][d] = (bf16) W[d][e], for three 768x768 matrices
__global__ void transpose_cast_w(const float* __restrict__ W0, const float* __restrict__ W1,
                                 const float* __restrict__ W2,
                                 short* __restrict__ T0, short* __restrict__ T1,
                                 short* __restrict__ T2) {
  const float* W = blockIdx.z == 0 ? W0 : (blockIdx.z == 1 ? W1 : W2);
  short* T = blockIdx.z == 0 ? T0 : (blockIdx.z == 1 ? T1 : T2);
  __shared__ float tile[32][33];
  int bx = blockIdx.x * 32, by = blockIdx.y * 32;
  int tx = threadIdx.x, ty = threadIdx.y;
  for (int r = ty; r < 32; r += 8)
    tile[r][tx] = W[(by + r) * D_ + bx + tx];
  __syncthreads();
  for (int r = ty; r < 32; r += 8)
    T[(bx + r) * D_ + by + tx] = f2bf(tile[tx][r]);
}

// C = A @ Bt^T over K (K % 64 == 0), batched via blockIdx.z. No LDS.
// Block = 4 waves 2x2; wave tile (TM*16)x(TN*16); block (TM*32)x(TN*32).
// EPI 0: QKV tri-output: n<768 -> Qb+bq ; <1536 -> Kb+bk ; else Vt transposed +bv
// EPI 2: bf16 out = exp(acc*scale)
// EPI 3: fp32 out = acc / rowsum[m], rowsum computed in-loop via ones-MFMA
template<int EPI, int TM, int TN>
__global__ __launch_bounds__(256)
void gemm_bt(const short* __restrict__ A, const short* __restrict__ Bt,
             void* __restrict__ C0v, short* __restrict__ C1, short* __restrict__ C2,
             const float* __restrict__ bias0, const float* __restrict__ bias1,
             const float* __restrict__ bias2,
             int K, int lda, int ldb, int ldc,
             long sA, long sB, long sC, float scale) {
  const int b = blockIdx.z;
  A += (long)b * sA;
  Bt += (long)b * sB;
  float* Cf = (float*)C0v + (long)b * sC;
  short* Cs = (short*)C0v + (long)b * sC;

  const int t = threadIdx.x;
  const int wave = t >> 6, lane = t & 63;
  const int lane16 = lane & 15, q = lane >> 4;
  const int m0 = blockIdx.y * (TM * 32), n0 = blockIdx.x * (TN * 32);
  const int wm = (wave >> 1) * (TM * 16), wn = (wave & 1) * (TN * 16);

  // per-lane fragment row pointers (k-contiguous), offset by this lane's q*8
  const short* Ar[TM];
  const short* Br[TN];
#pragma unroll
  for (int i = 0; i < TM; i++)
    Ar[i] = A + (long)(m0 + wm + i * 16 + lane16) * lda + q * 8;
#pragma unroll
  for (int j = 0; j < TN; j++)
    Br[j] = Bt + (long)(n0 + wn + j * 16 + lane16) * ldb + q * 8;

  float4v acc[TM][TN];
#pragma unroll
  for (int i = 0; i < TM; i++)
#pragma unroll
    for (int j = 0; j < TN; j++) acc[i][j] = {0.f, 0.f, 0.f, 0.f};

  // rowsum accumulators (EPI==3 only; dead otherwise)
  float4v acc_rs[TM];
#pragma unroll
  for (int i = 0; i < TM; i++) acc_rs[i] = {0.f, 0.f, 0.f, 0.f};
  short8 ones;
#pragma unroll
  for (int e = 0; e < 8; e++) ones[e] = (short)0x3F80;  // bf16 1.0

  for (int k0 = 0; k0 < K; k0 += 64) {
    // two independent fragment sets; loads of both issue before first MFMA use,
    // and the compiler overlaps next-iteration loads under these MFMAs (vmcnt).
    short8 af0[TM], bf0[TN], af1[TM], bf1[TN];
#pragma unroll
    for (int i = 0; i < TM; i++) af0[i] = *(const short8*)(Ar[i] + k0);
#pragma unroll
    for (int j = 0; j < TN; j++) bf0[j] = *(const short8*)(Br[j] + k0);
#pragma unroll
    for (int i = 0; i < TM; i++) af1[i] = *(const short8*)(Ar[i] + k0 + 32);
#pragma unroll
    for (int j = 0; j < TN; j++) bf1[j] = *(const short8*)(Br[j] + k0 + 32);

#pragma unroll
    for (int i = 0; i < TM; i++) {
#pragma unroll
      for (int j = 0; j < TN; j++)
        acc[i][j] = __builtin_amdgcn_mfma_f32_16x16x32_bf16(af0[i], bf0[j], acc[i][j], 0, 0, 0);
      if (EPI == 3)
        acc_rs[i] = __builtin_amdgcn_mfma_f32_16x16x32_bf16(af0[i], ones, acc_rs[i], 0, 0, 0);
    }
#pragma unroll
    for (int i = 0; i < TM; i++) {
#pragma unroll
      for (int j = 0; j < TN; j++)
        acc[i][j] = __builtin_amdgcn_mfma_f32_16x16x32_bf16(af1[i], bf1[j], acc[i][j], 0, 0, 0);
      if (EPI == 3)
        acc_rs[i] = __builtin_amdgcn_mfma_f32_16x16x32_bf16(af1[i], ones, acc_rs[i], 0, 0, 0);
    }
  }

#pragma unroll
  for (int i = 0; i < TM; i++) {
    int mrow = m0 + wm + i * 16 + q * 4;
    if (EPI == 0) {
#pragma unroll
      for (int j = 0; j < TN; j++) {
        int ncol = n0 + wn + j * 16 + lane16;   // tile-uniform branch: bounds %16
        if (ncol < 1536) {
          short* dst = ncol < 768 ? Cs : C1;
          const float* bs = ncol < 768 ? bias0 : bias1;
          int c = ncol < 768 ? ncol : ncol - 768;   // NOT `& 767` (768 != pow2)
#pragma unroll
          for (int rr = 0; rr < 4; rr++)
            dst[(long)(mrow + rr) * 768 + c] = f2bf(acc[i][j][rr] + bs[c]);
        } else {
          int e = ncol - 1536;
          float bv = bias2[e];
          short4v o;
#pragma unroll
          for (int rr = 0; rr < 4; rr++) o[rr] = f2bf(acc[i][j][rr] + bv);
          *(short4v*)&C2[(long)e * MS + mrow] = o;   // Vt[e][m], 8-B store
        }
      }
    } else if (EPI == 2) {
#pragma unroll
      for (int j = 0; j < TN; j++) {
        int ncol = n0 + wn + j * 16 + lane16;
#pragma unroll
        for (int rr = 0; rr < 4; rr++)
          Cs[(long)(mrow + rr) * ldc + ncol] = f2bf(__expf(acc[i][j][rr] * scale));
      }
    } else {
#pragma unroll
      for (int rr = 0; rr < 4; rr++) {
        float inv = 1.0f / acc_rs[i][rr];   // rowsum(mrow+rr), same C/D slot
#pragma unroll
        for (int j = 0; j < TN; j++) {
          int ncol = n0 + wn + j * 16 + lane16;
          Cf[(long)(mrow + rr) * ldc + ncol] = acc[i][j][rr] * inv;
        }
      }
    }
  }
}

extern "C" void kernel_launch(void* const* d_in, const int* in_sizes, int n_in,
                              void* d_out, int out_size, void* d_ws, size_t ws_size,
                              hipStream_t stream) {
  const float* x  = (const float*)d_in[0];
  const float* Wq = (const float*)d_in[1];
  const float* bq = (const float*)d_in[2];
  const float* Wk = (const float*)d_in[3];
  const float* bk = (const float*)d_in[4];
  const float* Wv = (const float*)d_in[5];
  const float* bv = (const float*)d_in[6];
  float* out = (float*)d_out;

  short* Xb  = (short*)d_ws;                     // [8192][768]
  short* WqT = Xb + (long)MS * D_;               // [2304][768] = WqT||WkT||WvT
  short* WkT = WqT + (long)D_ * D_;
  short* WvT = WkT + (long)D_ * D_;
  short* Qb  = WvT + (long)D_ * D_;              // [8192][768]
  short* Kb  = Qb + (long)MS * D_;               // [8192][768]
  short* Vt  = Kb + (long)MS * D_;               // [768][8192]
  short* Es  = Vt + (long)MS * D_;               // [4][2048][2048] exp(scores)

  cast_f32_bf16<<<(MS * D_) / 1024, 256, 0, stream>>>(x, Xb, MS * D_);
  transpose_cast_w<<<dim3(24, 24, 3), dim3(32, 8), 0, stream>>>(Wq, Wk, Wv, WqT, WkT, WvT);

  // Q||K||Vt = Xb @ [WqT;WkT;WvT]^T + biases  (128x128 tiles, 18x64 = 1152 blk)
  gemm_bt<0, 4, 4><<<dim3(2304 / 128, MS / 128, 1), 256, 0, stream>>>(
      Xb, WqT, Qb, Kb, Vt, bq, bk, bv,
      D_, D_, D_, D_, 0, 0, 0, 1.0f);
  // Es[b,q,k] = exp((Qb[b] @ Kb[b]^T)/sqrt(D)) -> bf16  (16x16x4 = 1024 blk)
  gemm_bt<2, 4, 4><<<dim3(S_ / 128, S_ / 128, B_), 256, 0, stream>>>(
      Qb, Kb, Es, nullptr, nullptr, nullptr, nullptr, nullptr,
      D_, D_, D_, S_,
      (long)S_ * D_, (long)S_ * D_, (long)S_ * S_, 1.0f / sqrtf((float)D_));
  // O[b,q,e] = (Es[b] @ V[b]) / rowsum  -> fp32  (6x16x4 = 384 blk)
  gemm_bt<3, 4, 4><<<dim3(D_ / 128, S_ / 128, B_), 256, 0, stream>>>(
      Es, Vt, out, nullptr, nullptr, nullptr, nullptr, nullptr,
      S_, S_, MS, D_,
      (long)S_ * S_, (long)S_, (long)S_ * D_, 1.0f);
}

// Round 8
// 211.792 us; speedup vs baseline: 1.9756x; 1.9756x over previous
//
#include <hip/hip_runtime.h>
#include <hip/hip_bf16.h>

// Self-attention: B=4, S=2048, D=768, fp32 in/out, bf16 MFMA internally.
// R8: back to R6's LDS+barrier structure (R7's no-LDS direct-global fragments
// were 2x WORSE — 16 scattered 64-B segments per load instr, latency-bound at
// MfmaUtil 10%). Change: 32x32x16 MFMA instead of 16x16x32 — 2x FLOP per LDS
// fragment byte, so per BK=64 wave-iter: 16 ds_read_b128 (~96 cyc) + 16 MFMA
// (~129 cyc) vs R6's 16 reads(~192)+32 MFMA(~155). LDS no longer rate-limits.
// A/B frag: m=lane&31, k=(lane>>5)*8+j (16-B k-contiguous load).
// C/D frag: col=lane&31, row=(r&3)+8*(r>>2)+4*(lane>>5)  [m74/m101].
// ws: Xb | WqT WkT WvT | Qb Kb Vt | Es

typedef __attribute__((ext_vector_type(8))) short short8;
typedef __attribute__((ext_vector_type(4))) short short4v;
typedef __attribute__((ext_vector_type(4))) float float4v;
typedef __attribute__((ext_vector_type(16))) float float16v;

static constexpr int B_ = 4, S_ = 2048, D_ = 768;
static constexpr int MS = B_ * S_;  // 8192

__device__ inline short f2bf(float f) {
  __hip_bfloat16 h = __float2bfloat16(f);
  union { __hip_bfloat16 h; short s; } u; u.h = h; return u.s;
}

typedef const __attribute__((address_space(1))) unsigned int g_u32;
typedef __attribute__((address_space(3))) unsigned int l_u32;

__device__ __forceinline__ void glds16(const short* g, short* l) {
  __builtin_amdgcn_global_load_lds((g_u32*)g, (l_u32*)l, 16, 0, 0);
}

__global__ __launch_bounds__(256)
void cast_f32_bf16(const float* __restrict__ x, short* __restrict__ y, int n) {
  int i = (blockIdx.x * 256 + threadIdx.x) * 4;
  if (i + 3 < n) {
    float4v v = *(const float4v*)(x + i);
    short4v o;
    o.x = f2bf(v.x); o.y = f2bf(v.y); o.z = f2bf(v.z); o.w = f2bf(v.w);
    *(short4v*)(y + i) = o;
  }
}

// T[e][d] = (bf16) W[d][e], for three 768x768 matrices
__global__ void transpose_cast_w(const float* __restrict__ W0, const float* __restrict__ W1,
                                 const float* __restrict__ W2,
                                 short* __restrict__ T0, short* __restrict__ T1,
                                 short* __restrict__ T2) {
  const float* W = blockIdx.z == 0 ? W0 : (blockIdx.z == 1 ? W1 : W2);
  short* T = blockIdx.z == 0 ? T0 : (blockIdx.z == 1 ? T1 : T2);
  __shared__ float tile[32][33];
  int bx = blockIdx.x * 32, by = blockIdx.y * 32;
  int tx = threadIdx.x, ty = threadIdx.y;
  for (int r = ty; r < 32; r += 8)
    tile[r][tx] = W[(by + r) * D_ + bx + tx];
  __syncthreads();
  for (int r = ty; r < 32; r += 8)
    T[(bx + r) * D_ + by + tx] = f2bf(tile[tx][r]);
}

// C = A @ Bt^T over K (K%64==0), batched via blockIdx.z. 128x128 block,
// 4 waves 2x2, wave tile 64x64 = 2x2 MFMAs of 32x32x16.
// LDS rows 128 B = 8 x 16-B chunks, XOR-swizzled at the global source:
// chunk g of row r staged at position g^(r&7); fragment chunk c reads c^(R&7).
// K-loop: B1(drain stage k) -> ds_read frags -> B2 -> glds stage k+1 -> MFMA.
// EPI 0: QKV tri-output: n<768 -> Qb+bq ; <1536 -> Kb+bk ; else Vt transposed +bv
// EPI 2: bf16 out = exp(acc*scale)
// EPI 3: fp32 out = acc / rowsum[m], rowsum via ones-MFMA in-loop
template<int EPI>
__global__ __launch_bounds__(256)
void gemm_bt(const short* __restrict__ A, const short* __restrict__ Bt,
             void* __restrict__ C0v, short* __restrict__ C1, short* __restrict__ C2,
             const float* __restrict__ bias0, const float* __restrict__ bias1,
             const float* __restrict__ bias2,
             int K, int lda, int ldb, int ldc,
             long sA, long sB, long sC, float scale) {
  const int b = blockIdx.z;
  A += (long)b * sA;
  Bt += (long)b * sB;
  float* Cf = (float*)C0v + (long)b * sC;
  short* Cs = (short*)C0v + (long)b * sC;

  __shared__ short As[128 * 64];   // [128 rows][64 shorts = 128 B]
  __shared__ short Bs[128 * 64];

  const int t = threadIdx.x;
  const int wave = t >> 6, lane = t & 63;
  const int l31 = lane & 31, kg = lane >> 5;   // MFMA operand row / k-group
  const int m0 = blockIdx.y * 128, n0 = blockIdx.x * 128;
  const int wm = (wave >> 1) * 64, wn = (wave & 1) * 64;
  const int rsub = lane >> 3;          // staging: row within 8-row wave-instr
  const int g = (lane & 7) ^ rsub;     // staging: swizzled source chunk

  auto stage = [&](int kk) {
#pragma unroll
    for (int i = wave; i < 16; i += 4)
      glds16(A + (long)(m0 + i * 8 + rsub) * lda + kk + g * 8, &As[i * 512]);
#pragma unroll
    for (int i = wave; i < 16; i += 4)
      glds16(Bt + (long)(n0 + i * 8 + rsub) * ldb + kk + g * 8, &Bs[i * 512]);
  };

  stage(0);  // prologue; acc zero-init overlaps with the loads

  float16v acc[2][2];
#pragma unroll
  for (int i = 0; i < 2; i++)
#pragma unroll
    for (int j = 0; j < 2; j++)
#pragma unroll
      for (int r = 0; r < 16; r++) acc[i][j][r] = 0.f;

  float16v acc_rs[2];  // EPI==3 only; dead otherwise
#pragma unroll
  for (int i = 0; i < 2; i++)
#pragma unroll
    for (int r = 0; r < 16; r++) acc_rs[i][r] = 0.f;
  short8 ones;
#pragma unroll
  for (int e = 0; e < 8; e++) ones[e] = (short)0x3F80;  // bf16 1.0

  for (int k0 = 0; k0 < K; k0 += 64) {
    __syncthreads();  // B1: drains stage(k0) [vmcnt(0)] + wave sync

    short8 af[4][2], bfr[4][2];
#pragma unroll
    for (int s = 0; s < 4; s++) {
      int c = s * 2 + kg;  // 16-B chunk index of this lane's k-slice
#pragma unroll
      for (int i = 0; i < 2; i++) {
        int Ra = wm + i * 32 + l31;
        af[s][i] = *(const short8*)&As[Ra * 64 + ((c ^ (Ra & 7)) * 8)];
        int Rb = wn + i * 32 + l31;
        bfr[s][i] = *(const short8*)&Bs[Rb * 64 + ((c ^ (Rb & 7)) * 8)];
      }
    }
    __syncthreads();  // B2: all waves done reading LDS

    if (k0 + 64 < K) stage(k0 + 64);  // async; overlaps the MFMAs below

#pragma unroll
    for (int s = 0; s < 4; s++) {
#pragma unroll
      for (int i = 0; i < 2; i++) {
#pragma unroll
        for (int j = 0; j < 2; j++)
          acc[i][j] = __builtin_amdgcn_mfma_f32_32x32x16_bf16(af[s][i], bfr[s][j], acc[i][j], 0, 0, 0);
        if (EPI == 3)
          acc_rs[i] = __builtin_amdgcn_mfma_f32_32x32x16_bf16(af[s][i], ones, acc_rs[i], 0, 0, 0);
      }
    }
  }

#pragma unroll
  for (int i = 0; i < 2; i++) {
    if (EPI == 3) {
#pragma unroll
      for (int r = 0; r < 16; r++) {
        int row = m0 + wm + i * 32 + (r & 3) + 8 * (r >> 2) + 4 * kg;
        float inv = 1.0f / acc_rs[i][r];
#pragma unroll
        for (int j = 0; j < 2; j++) {
          int ncol = n0 + wn + j * 32 + l31;
          Cf[(long)row * ldc + ncol] = acc[i][j][r] * inv;
        }
      }
    } else {
#pragma unroll
      for (int j = 0; j < 2; j++) {
        int ncol = n0 + wn + j * 32 + l31;
        if (EPI == 0) {
          if (ncol < 1536) {   // 768 is a multiple of 32 -> branch wave-uniform
            short* dst = ncol < 768 ? Cs : C1;
            const float* bs = ncol < 768 ? bias0 : bias1;
            int c = ncol < 768 ? ncol : ncol - 768;   // NOT `& 767`
            float bvv = bs[c];
#pragma unroll
            for (int r = 0; r < 16; r++) {
              int row = m0 + wm + i * 32 + (r & 3) + 8 * (r >> 2) + 4 * kg;
              dst[(long)row * 768 + c] = f2bf(acc[i][j][r] + bvv);
            }
          } else {
            int e = ncol - 1536;
            float bvv = bias2[e];
#pragma unroll
            for (int gg = 0; gg < 4; gg++) {
              int mbase = m0 + wm + i * 32 + 8 * gg + 4 * kg;
              short4v o;
#pragma unroll
              for (int rr = 0; rr < 4; rr++) o[rr] = f2bf(acc[i][j][4 * gg + rr] + bvv);
              *(short4v*)&C2[(long)e * MS + mbase] = o;   // Vt[e][m], 8-B store
            }
          }
        } else {  // EPI == 2
#pragma unroll
          for (int r = 0; r < 16; r++) {
            int row = m0 + wm + i * 32 + (r & 3) + 8 * (r >> 2) + 4 * kg;
            Cs[(long)row * ldc + ncol] = f2bf(__expf(acc[i][j][r] * scale));
          }
        }
      }
    }
  }
}

extern "C" void kernel_launch(void* const* d_in, const int* in_sizes, int n_in,
                              void* d_out, int out_size, void* d_ws, size_t ws_size,
                              hipStream_t stream) {
  const float* x  = (const float*)d_in[0];
  const float* Wq = (const float*)d_in[1];
  const float* bq = (const float*)d_in[2];
  const float* Wk = (const float*)d_in[3];
  const float* bk = (const float*)d_in[4];
  const float* Wv = (const float*)d_in[5];
  const float* bv = (const float*)d_in[6];
  float* out = (float*)d_out;

  short* Xb  = (short*)d_ws;                     // [8192][768]
  short* WqT = Xb + (long)MS * D_;               // [2304][768] = WqT||WkT||WvT
  short* WkT = WqT + (long)D_ * D_;
  short* WvT = WkT + (long)D_ * D_;
  short* Qb  = WvT + (long)D_ * D_;              // [8192][768]
  short* Kb  = Qb + (long)MS * D_;               // [8192][768]
  short* Vt  = Kb + (long)MS * D_;               // [768][8192]
  short* Es  = Vt + (long)MS * D_;               // [4][2048][2048] exp(scores)

  cast_f32_bf16<<<(MS * D_) / 1024, 256, 0, stream>>>(x, Xb, MS * D_);
  transpose_cast_w<<<dim3(24, 24, 3), dim3(32, 8), 0, stream>>>(Wq, Wk, Wv, WqT, WkT, WvT);

  // Q||K||Vt = Xb @ [WqT;WkT;WvT]^T + biases  (128x128 tiles, 18x64 = 1152 blk)
  gemm_bt<0><<<dim3(2304 / 128, MS / 128, 1), 256, 0, stream>>>(
      Xb, WqT, Qb, Kb, Vt, bq, bk, bv,
      D_, D_, D_, D_, 0, 0, 0, 1.0f);
  // Es[b,q,k] = exp((Qb[b] @ Kb[b]^T)/sqrt(D)) -> bf16  (16x16x4 = 1024 blk)
  gemm_bt<2><<<dim3(S_ / 128, S_ / 128, B_), 256, 0, stream>>>(
      Qb, Kb, Es, nullptr, nullptr, nullptr, nullptr, nullptr,
      D_, D_, D_, S_,
      (long)S_ * D_, (long)S_ * D_, (long)S_ * S_, 1.0f / sqrtf((float)D_));
  // O[b,q,e] = (Es[b] @ V[b]) / rowsum  -> fp32  (6x16x4 = 384 blk)
  gemm_bt<3><<<dim3(D_ / 128, S_ / 128, B_), 256, 0, stream>>>(
      Es, Vt, out, nullptr, nullptr, nullptr, nullptr, nullptr,
      S_, S_, MS, D_,
      (long)S_ * S_, (long)S_, (long)S_ * D_, 1.0f);
}